// Round 9
// baseline (5853.305 us; speedup 1.0000x reference)
//
#include <hip/hip_runtime.h>
#include <hip/hip_cooperative_groups.h>
#include <cstddef>
#include <cstdint>

namespace cg = cooperative_groups;

// Round 9: R8 mega-kernel with (1) occupancy-clamped cooperative grid,
// (2) CHECKED launch + per-phase fallback (R8 failed because the coop launch
// errored — likely CooperativeLaunchTooLarge — and the code ignored the rc).
// GEMM front-end unchanged from R7.

constexpr int kN  = 10000;
constexpr int kE  = 320000;
constexpr int kNH = 256;
constexpr int kC  = 16;
constexpr int kK  = 64;
constexpr int GRAM_PARTS = 256;   // 40-row chunks

struct SelState {
  int bin1[2]; int rem1[2];
  float thr_base;
};

typedef short bf16x8 __attribute__((ext_vector_type(8)));
typedef float f32x4 __attribute__((ext_vector_type(4)));
typedef ushort ushort8 __attribute__((ext_vector_type(8)));

__device__ __forceinline__ ushort f2bf(float x) {
  unsigned u = __float_as_uint(x);
  unsigned r = (u + 0x7fffu + ((u >> 16) & 1u)) >> 16;   // RNE
  return (ushort)r;
}
__device__ __forceinline__ float bf2f(ushort h) {
  return __uint_as_float((unsigned)h << 16);
}
__device__ __forceinline__ int swz(int row, int byteInRow) {
  int chunk = (byteInRow >> 4) ^ ((row >> 1) & 3);
  return row * 64 + (chunk << 4) + (byteInRow & 15);
}

__global__ void split_bf(const float* __restrict__ B, ushort* __restrict__ hi,
                         ushort* __restrict__ lo, int N2, int K, int Kp)
{
  int t = blockIdx.x * 256 + threadIdx.x;
  if (t >= N2 * Kp) return;
  int r = t / Kp, c = t % Kp;
  float v = (c < K) ? B[(size_t)r * K + c] : 0.f;
  ushort h = f2bf(v);
  hi[t] = h;
  lo[t] = f2bf(v - bf2f(h));
}

// ===== MFMA GEMM (unchanged) =====
template<int BN, bool ALO>
__global__ __launch_bounds__(256) void gemm_v3(
    const float* __restrict__ A, const ushort* __restrict__ Bhg,
    const ushort* __restrict__ Blg, const float* __restrict__ bias,
    float* __restrict__ out, int M, int K, int Kp, int KR, int outStride)
{
  __shared__ __align__(16) char sAh[64 * 64];
  __shared__ __align__(16) char sAl[ALO ? 64 * 64 : 16];
  __shared__ __align__(16) char sBh[BN * 64];
  __shared__ __align__(16) char sBl[BN * 64];
  const int t = threadIdx.x;
  const int lane = t & 63, w = t >> 6;
  const int bm = blockIdx.x * 64;
  const int k0 = blockIdx.z * KR;
  const int kend = min(K, k0 + KR);
  out += (size_t)blockIdx.z * M * outStride;
  constexpr int WN = BN / 64;
  constexpr int RB = WN;
  const int wc = (w % WN) * 64;
  const int wr = (w / WN) * (RB * 16);
  const int l15 = lane & 15;
  const int lByte = (lane >> 4) * 16;
  const int ar = t >> 2, ac = t & 3;

  f32x4 acc[RB][4] = {};
  for (int kt = k0; kt < kend; kt += 32) {
    {
      int gr = bm + ar, gk = kt + ac * 8;
      float v[8];
      if (gr < M && gk + 8 <= kend) {
        float4 v0 = *reinterpret_cast<const float4*>(A + (size_t)gr * K + gk);
        float4 v1 = *reinterpret_cast<const float4*>(A + (size_t)gr * K + gk + 4);
        v[0] = v0.x; v[1] = v0.y; v[2] = v0.z; v[3] = v0.w;
        v[4] = v1.x; v[5] = v1.y; v[6] = v1.z; v[7] = v1.w;
      } else {
#pragma unroll
        for (int q = 0; q < 8; q++)
          v[q] = (gr < M && gk + q < kend) ? A[(size_t)gr * K + gk + q] : 0.f;
      }
      ushort8 h8, l8;
#pragma unroll
      for (int q = 0; q < 8; q++) {
        ushort h = f2bf(v[q]); h8[q] = h;
        if (ALO) l8[q] = f2bf(v[q] - bf2f(h));
      }
      *reinterpret_cast<ushort8*>(sAh + swz(ar, ac * 16)) = h8;
      if (ALO) *reinterpret_cast<ushort8*>(sAl + swz(ar, ac * 16)) = l8;
    }
#pragma unroll
    for (int i2 = 0; i2 < BN / 64; i2++) {
      int idx = t + i2 * 256;
      int r = idx >> 2, c = idx & 3;
      size_t gb = (size_t)r * Kp + kt + c * 8;
      ushort8 hv = *reinterpret_cast<const ushort8*>(Bhg + gb);
      ushort8 lv = *reinterpret_cast<const ushort8*>(Blg + gb);
      *reinterpret_cast<ushort8*>(sBh + swz(r, c * 16)) = hv;
      *reinterpret_cast<ushort8*>(sBl + swz(r, c * 16)) = lv;
    }
    __syncthreads();
    bf16x8 bh[4], bl[4];
#pragma unroll
    for (int nbq = 0; nbq < 4; nbq++) {
      int rr = wc + nbq * 16 + l15;
      bh[nbq] = *reinterpret_cast<const bf16x8*>(sBh + swz(rr, lByte));
      bl[nbq] = *reinterpret_cast<const bf16x8*>(sBl + swz(rr, lByte));
    }
#pragma unroll
    for (int rb = 0; rb < RB; rb++) {
      int rr = wr + rb * 16 + l15;
      bf16x8 ah = *reinterpret_cast<const bf16x8*>(sAh + swz(rr, lByte));
#pragma unroll
      for (int nbq = 0; nbq < 4; nbq++) {
        acc[rb][nbq] = __builtin_amdgcn_mfma_f32_16x16x32_bf16(ah, bh[nbq], acc[rb][nbq], 0, 0, 0);
        acc[rb][nbq] = __builtin_amdgcn_mfma_f32_16x16x32_bf16(ah, bl[nbq], acc[rb][nbq], 0, 0, 0);
      }
      if (ALO) {
        bf16x8 al = *reinterpret_cast<const bf16x8*>(sAl + swz(rr, lByte));
#pragma unroll
        for (int nbq = 0; nbq < 4; nbq++)
          acc[rb][nbq] = __builtin_amdgcn_mfma_f32_16x16x32_bf16(al, bh[nbq], acc[rb][nbq], 0, 0, 0);
      }
    }
    __syncthreads();
  }
#pragma unroll
  for (int rb = 0; rb < RB; rb++) {
#pragma unroll
    for (int nbq = 0; nbq < 4; nbq++) {
      int colg = wc + nbq * 16 + l15;
      float bv = bias ? bias[colg] : 0.f;
#pragma unroll
      for (int jj = 0; jj < 4; jj++) {
        int rowg = bm + wr + rb * 16 + (lane >> 4) * 4 + jj;
        if (rowg < M) out[(size_t)rowg * outStride + colg] = acc[rb][nbq][jj] + bv;
      }
    }
  }
}

__global__ void reduce_raw(const float4* __restrict__ Pa, const float4* px,
                           const float* __restrict__ ba, const float* __restrict__ b1,
                           float4* rawOut)
{
  int t = blockIdx.x * 256 + threadIdx.x;
  if (t >= kN * kNH / 4) return;
  const int sl = kN * kNH / 4;
  float4 s = Pa[t];
#pragma unroll
  for (int p = 1; p < 6; p++) {
    float4 q = Pa[t + (size_t)p * sl];
    s.x += q.x; s.y += q.y; s.z += q.z; s.w += q.w;
  }
  float4 pxv = px[t];
  int c4 = t & 63;
  float4 vba = reinterpret_cast<const float4*>(ba)[c4];
  float4 vb1 = reinterpret_cast<const float4*>(b1)[c4];
  float4 r;
  r.x = fmaxf(0.5f * (s.x + vba.x) + 0.5f * (pxv.x + vb1.x), 0.f);
  r.y = fmaxf(0.5f * (s.y + vba.y) + 0.5f * (pxv.y + vb1.y), 0.f);
  r.z = fmaxf(0.5f * (s.z + vba.z) + 0.5f * (pxv.z + vb1.z), 0.f);
  r.w = fmaxf(0.5f * (s.w + vba.w) + 0.5f * (pxv.w + vb1.w), 0.f);
  rawOut[t] = r;
}

// =================== mega args ===================
struct MegaArgs {
  const float* raw;
  const float* lin2_w; const float* lin2_b;
  const int* row; const int* col;
  const float* aw; const float* ew;
  const float* lnw; const float* lnb;
  const float* left_w; const float* att_w;
  const float* ci; const float* conf_p; const float* b_param;
  const float* Wm;
  float* h16; int* yhat; float* nei; float* hC; float* lx; float* conf;
  int* cntR; int* cntC; int* fillR; int* fillC; int* startR; int* startC;
  int* eR; int* eC; int* othR; int* othC;
  float* Va; float* Vb; float* Ua; float* Ub; float* T;
  float* score; float* G; float* Gi; float* Gp; float* hTX; float* Hp;
  int* hist1; int* h2a; int* h2b;
  float* P;
  SelState* sel;
  float* out;
};

// U/V ping-pong state entering iteration j (j=4 -> final: Ua, Va)
__device__ __forceinline__ void uv_at(const MegaArgs& a, int j,
                                      float*& Ucur, float*& Unxt,
                                      float*& Vcur, float*& Vnxt)
{
  int uU = (j >= 1) + (j >= 3);
  int uV = (j >= 2) + (j >= 4);
  Ucur = (uU & 1) ? a.Ub : a.Ua; Unxt = (uU & 1) ? a.Ua : a.Ub;
  Vcur = (uV & 1) ? a.Vb : a.Va; Vnxt = (uV & 1) ? a.Va : a.Vb;
}

// ---- phase helpers ----
__device__ void gram2_dev(const float* M, const float* hc, float* P, int b, float* shm)
{
  float* sM = shm;
  float* sH = shm + 512;
  const int t = threadIdx.x;
  const int aG = t >> 2, cG0 = (t & 3) * 16;
  const int aH = t >> 4, cH0 = (t & 15) * 4;
  float accG[16]; float accH[4];
#pragma unroll
  for (int q = 0; q < 16; q++) accG[q] = 0.f;
#pragma unroll
  for (int q = 0; q < 4; q++) accH[q] = 0.f;
  int r0 = b * 40, r1 = min(kN, r0 + 40);
  for (int rb = r0; rb < r1; rb += 8) {
    int nb2 = min(8, r1 - rb);
    __syncthreads();
    for (int q = t; q < nb2 * 64; q += 256) sM[q] = M[(size_t)rb * 64 + q];
    for (int q = t; q < nb2 * 16; q += 256) sH[q] = hc[(size_t)rb * 16 + q];
    __syncthreads();
    for (int r = 0; r < nb2; r++) {
      float avG = sM[r * 64 + aG];
      const float* sbG = &sM[r * 64 + cG0];
#pragma unroll
      for (int q = 0; q < 16; q++) accG[q] += avG * sbG[q];
      float avH = sH[r * 16 + aH];
      const float* sbH = &sM[r * 64 + cH0];
#pragma unroll
      for (int q = 0; q < 4; q++) accH[q] += avH * sbH[q];
    }
  }
  float* p1 = P + (size_t)b * 5120 + aG * 64 + cG0;
#pragma unroll
  for (int q = 0; q < 16; q++) p1[q] = accG[q];
  float* p2 = P + (size_t)b * 5120 + 4096 + aH * 64 + cH0;
#pragma unroll
  for (int q = 0; q < 4; q++) p2[q] = accH[q];
}

__device__ void inverse_dev(const float* G, float* Gi, float alpha, float beta,
                            const float* hTX, float* Gp, float* Hp, float* shm)
{
  float* A = shm;
  float* prow = shm + 8448;
  float* fcol = shm + 8576;
  const int t = threadIdx.x;
  for (int q = t; q < 64 * 128; q += 256) {
    int r = q >> 7, c = q & 127;
    float v;
    if (c < 64) v = alpha * G[r * 64 + c] + ((c == r) ? beta : 0.f);
    else        v = (c - 64 == r) ? 1.f : 0.f;
    A[r * 132 + c] = v;
  }
  __syncthreads();
  const int i  = t >> 2;
  const int c0 = (t & 3) * 32;
  for (int k = 0; k < 64; k++) {
    if (t < 128) prow[t] = A[k * 132 + t];
    else if (t < 192) fcol[t - 128] = A[(t - 128) * 132 + k];
    __syncthreads();
    float pinv = 1.f / prow[k];
    float f = fcol[i];
    float4* Ar = reinterpret_cast<float4*>(&A[i * 132 + c0]);
    const float4* pr = reinterpret_cast<const float4*>(&prow[c0]);
    if (i == k) {
#pragma unroll
      for (int q = 0; q < 8; q++) {
        float4 p = pr[q];
        p.x *= pinv; p.y *= pinv; p.z *= pinv; p.w *= pinv;
        Ar[q] = p;
      }
    } else {
#pragma unroll
      for (int q = 0; q < 8; q++) {
        float4 p = pr[q]; float4 av = Ar[q];
        av.x -= f * (p.x * pinv); av.y -= f * (p.y * pinv);
        av.z -= f * (p.z * pinv); av.w -= f * (p.w * pinv);
        Ar[q] = av;
      }
    }
    __syncthreads();
  }
  for (int q = t; q < 4096; q += 256) Gi[q] = A[(q >> 6) * 132 + 64 + (q & 63)];
  if (Gp) {
    for (int q = t; q < 4096; q += 256) {
      int r = q >> 6, k = q & 63;
      float s = 0.f;
#pragma unroll 8
      for (int jj = 0; jj < 64; jj++) s += G[r * 64 + jj] * A[jj * 132 + 64 + k];
      Gp[q] = s;
    }
    for (int q = t; q < 1024; q += 256) {
      int c = q >> 6, k = q & 63;
      float s = 0.f;
#pragma unroll 8
      for (int jj = 0; jj < 64; jj++) s += hTX[c * 64 + jj] * A[jj * 132 + 64 + k];
      Hp[q] = 0.1f * s;  // EPS
    }
  }
}

__device__ void scan_dev(const int* h0, const int* h1, int stage, SelState* sel, int* shm)
{
  const int t = threadIdx.x;
  int* part = shm;
  int* fbs  = shm + 256;
  float* qsh = (float*)(shm + 258);
  for (int tgt = 0; tgt < 2; tgt++) {
    const int* H = tgt ? h1 : h0;
    const int4* H4 = reinterpret_cast<const int4*>(H + t * 256);
    int R = (stage == 1) ? (tgt ? (3 * kE / 4) : (kE / 4)) : sel->rem1[tgt];
    int lsum = 0;
    for (int b = 0; b < 64; b++) { int4 v = H4[b]; lsum += v.x + v.y + v.z + v.w; }
    part[t] = lsum;
    __syncthreads();
    for (int off = 1; off < 256; off <<= 1) {
      int v = part[t];
      int u = (t >= off) ? part[t - off] : 0;
      __syncthreads();
      part[t] = v + u;
      __syncthreads();
    }
    int cum = part[t] - lsum;
    int fb = -1, fr = 0;
    for (int b = 0; b < 64; b++) {
      int4 v = H4[b];
      int bb = t * 256 + b * 4;
      if (fb < 0 && R >= cum && R < cum + v.x) { fb = bb;     fr = R - cum; } cum += v.x;
      if (fb < 0 && R >= cum && R < cum + v.y) { fb = bb + 1; fr = R - cum; } cum += v.y;
      if (fb < 0 && R >= cum && R < cum + v.z) { fb = bb + 2; fr = R - cum; } cum += v.z;
      if (fb < 0 && R >= cum && R < cum + v.w) { fb = bb + 3; fr = R - cum; } cum += v.w;
    }
    if (fb >= 0) {
      fbs[tgt] = fb;
      if (stage == 1) { sel->bin1[tgt] = fb; sel->rem1[tgt] = fr; }
    }
    __syncthreads();
    if (stage == 2 && t == 0) {
      unsigned u = ((unsigned)sel->bin1[tgt] << 16) | (unsigned)fbs[tgt];
      qsh[tgt] = __uint_as_float(u);
    }
    __syncthreads();
  }
  if (stage == 2 && t == 0) {
    float q1 = qsh[0], q3 = qsh[1];
    sel->thr_base = q3 + 1.5f * (q3 - q1);
  }
}

__device__ void spmm_dev(const float* vals, const float* score, const float* conf,
                         const SelState* sel, const float* bp,
                         const int* start, const int* eids, const int* oth,
                         const float* Msrc, float* T, int wid0, int wstride)
{
  int lane = threadIdx.x & 63;
  float tb = 0.f, bp0 = 0.f;
  if (!vals) { tb = sel->thr_base; bp0 = bp[0]; }
  for (int wid = wid0; wid < kN; wid += wstride) {
    int p = start[wid], pend = start[wid + 1];
    float acc = 0.f;
    for (; p + 4 <= pend; p += 4) {
      int e0 = eids[p], e1 = eids[p + 1], e2 = eids[p + 2], e3 = eids[p + 3];
      int o0 = oth[p], o1 = oth[p + 1], o2 = oth[p + 2], o3 = oth[p + 3];
      float m0 = Msrc[(size_t)o0 * 64 + lane];
      float m1 = Msrc[(size_t)o1 * 64 + lane];
      float m2 = Msrc[(size_t)o2 * 64 + lane];
      float m3 = Msrc[(size_t)o3 * 64 + lane];
      float v0, v1, v2, v3;
      if (vals) { v0 = vals[e0]; v1 = vals[e1]; v2 = vals[e2]; v3 = vals[e3]; }
      else {
        float s0 = score[e0], s1 = score[e1], s2 = score[e2], s3 = score[e3];
        v0 = (s0 * s0 < tb * conf[e0]) ? (s0 + bp0) : 0.f;
        v1 = (s1 * s1 < tb * conf[e1]) ? (s1 + bp0) : 0.f;
        v2 = (s2 * s2 < tb * conf[e2]) ? (s2 + bp0) : 0.f;
        v3 = (s3 * s3 < tb * conf[e3]) ? (s3 + bp0) : 0.f;
      }
      acc += v0 * m0 + v1 * m1 + v2 * m2 + v3 * m3;
    }
    for (; p < pend; ++p) {
      int e = eids[p];
      float v;
      if (vals) v = vals[e];
      else { float sc = score[e]; v = (sc * sc < tb * conf[e]) ? (sc + bp0) : 0.f; }
      acc += v * Msrc[(size_t)oth[p] * 64 + lane];
    }
    T[(size_t)wid * 64 + lane] = acc;
  }
}

__device__ void outf_dev(const MegaArgs& a, const float* T, const float* X,
                         float* Out, int gtid, int gsz)
{
  for (int i = gtid; i < 65536; i += gsz) { a.hist1[i] = 0; a.h2a[i] = 0; a.h2b[i] = 0; }
  for (int t = gtid; t < kN * 16; t += gsz) {
    int i = t >> 4, kq = t & 15;
    const float* ti = T + (size_t)i * 64;
    const float4* G4 = reinterpret_cast<const float4*>(a.Gi);
    float4 s = make_float4(0.f, 0.f, 0.f, 0.f);
#pragma unroll 8
    for (int jj = 0; jj < 64; jj++) {
      float tv = ti[jj];
      float4 g = G4[jj * 16 + kq];
      s.x += tv * g.x; s.y += tv * g.y; s.z += tv * g.z; s.w += tv * g.w;
    }
    if (X) {
      const float* xi = X + (size_t)i * 64;
      const float4* Gp4 = reinterpret_cast<const float4*>(a.Gp);
      float4 s2 = make_float4(0.f, 0.f, 0.f, 0.f);
#pragma unroll 8
      for (int jj = 0; jj < 64; jj++) {
        float xv = xi[jj];
        float4 g = Gp4[jj * 16 + kq];
        s2.x += xv * g.x; s2.y += xv * g.y; s2.z += xv * g.z; s2.w += xv * g.w;
      }
      s.x += s2.x; s.y += s2.y; s.z += s2.z; s.w += s2.w;
      const float4* Hp4 = reinterpret_cast<const float4*>(a.Hp);
      float4 s3 = make_float4(0.f, 0.f, 0.f, 0.f);
#pragma unroll
      for (int c = 0; c < 16; c++) {
        float hv = a.hC[(size_t)i * 16 + c];
        float4 g = Hp4[c * 16 + kq];
        s3.x += hv * g.x; s3.y += hv * g.y; s3.z += hv * g.z; s3.w += hv * g.w;
      }
      s.x += s3.x; s.y += s3.y; s.z += s3.z; s.w += s3.w;
    }
    *reinterpret_cast<float4*>(Out + (size_t)i * 64 + kq * 4) = s;
  }
}

__device__ void reduce_dev(const MegaArgs& a, int gtid, int gsz)
{
  for (int c = gtid; c < 5120; c += gsz) {
    float s = 0.f;
    for (int p = 0; p < GRAM_PARTS; p++) s += a.P[(size_t)p * 5120 + c];
    if (c < 4096) a.G[c] = s;
    else a.hTX[c - 4096] = s;
  }
}

// ---- one phase of the pipeline; shared by coop kernel and fallback ----
__device__ void run_phase(const MegaArgs& a, int phase, int j, float* smem)
{
  const int tid = threadIdx.x;
  const int bid = blockIdx.x;
  const int nb  = gridDim.x;
  const int gtid = bid * 256 + tid;
  const int gsz = nb * 256;
  float *Ucur, *Unxt, *Vcur, *Vnxt;
  uv_at(a, j, Ucur, Unxt, Vcur, Vnxt);
  bool up = ((j & 1) == 0);
  const float* Ma   = up ? Ucur : Vcur;
  const float* Mb   = up ? Vcur : Ucur;
  const float* Moth = up ? Vcur : Ucur;
  const float* Xcur = up ? Ucur : Vcur;
  float* Xout       = up ? Unxt : Vnxt;

  switch (phase) {
  case 0: {  // zero cnt/fill + h16+argmax + zero nei + zero hists
    for (int i = gtid; i < kN; i += gsz) { a.cntR[i] = 0; a.cntC[i] = 0; a.fillR[i] = 0; a.fillC[i] = 0; }
    for (int t = gtid; t < kN * 16; t += gsz) {
      int i = t >> 4, jj = t & 15;
      const float4* av4 = reinterpret_cast<const float4*>(a.raw + (size_t)i * 256);
      const float4* bv4 = reinterpret_cast<const float4*>(a.lin2_w + (size_t)jj * 256);
      float s = a.lin2_b[jj];
#pragma unroll 8
      for (int q = 0; q < 64; q++) {
        float4 av = av4[q], bv = bv4[q];
        s += av.x * bv.x + av.y * bv.y + av.z * bv.z + av.w * bv.w;
      }
      a.h16[t] = s;
      float m = s; int am = jj;
#pragma unroll
      for (int off = 1; off < 16; off <<= 1) {
        float om = __shfl_xor(m, off);
        int oa = __shfl_xor(am, off);
        if (om > m || (om == m && oa < am)) { m = om; am = oa; }
      }
      if (jj == 0) a.yhat[i] = am;
      a.nei[t] = 0.f;
    }
    for (int i = gtid; i < 65536; i += gsz) { a.hist1[i] = 0; a.h2a[i] = 0; a.h2b[i] = 0; }
  } break;
  case 1: {  // csr_count + scatter_nei
    for (int e = gtid; e < kE; e += gsz) {
      int r = a.row[e], c = a.col[e];
      atomicAdd(&a.cntR[r], 1);
      atomicAdd(&a.cntC[c], 1);
      atomicAdd(&a.nei[(size_t)r * 16 + a.yhat[c]], a.aw[e]);
    }
  } break;
  case 2: {  // block0: csr scans; others: norm_xn_h
    if (bid == 0) {
      int* part = (int*)smem;
      for (int pass = 0; pass < 2; ++pass) {
        const int* cnt = pass ? a.cntC : a.cntR;
        int* start = pass ? a.startC : a.startR;
        int bbase = tid * 40;
        int s = 0;
        for (int q = 0; q < 40; q++) { int idx = bbase + q; if (idx < kN) s += cnt[idx]; }
        part[tid] = s;
        __syncthreads();
        for (int off = 1; off < 256; off <<= 1) {
          int v = part[tid];
          int u = (tid >= off) ? part[tid - off] : 0;
          __syncthreads();
          part[tid] = v + u;
          __syncthreads();
        }
        int run = part[tid] - s;
        for (int q = 0; q < 40; q++) {
          int idx = bbase + q;
          if (idx < kN) { start[idx] = run; run += cnt[idx]; }
        }
        if (tid == 255) start[kN] = part[255];
        __syncthreads();
      }
    } else {
      for (int i = (bid - 1) * 256 + tid; i < kN; i += (nb - 1) * 256) {
        float nv[16]; float s = 0.f;
#pragma unroll
        for (int c = 0; c < 16; c++) { nv[c] = a.nei[(size_t)i * 16 + c]; s += nv[c]; }
        float inv = (s != 0.f) ? 1.f / s : 0.f;
#pragma unroll
        for (int jj = 0; jj < 16; jj++) {
          float xn = a.lnb[jj];
#pragma unroll
          for (int c = 0; c < 16; c++) xn += (nv[c] * inv) * a.lnw[jj * 16 + c];
          xn = fmaxf(xn, 0.f);
          a.hC[(size_t)i * 16 + jj] = 0.5f * a.h16[(size_t)i * 16 + jj] + 0.5f * xn;
        }
      }
    }
  } break;
  case 3: {  // csr_fill + lx
    for (int e = gtid; e < kE; e += gsz) {
      int r = a.row[e], c = a.col[e];
      int pr = a.startR[r] + atomicAdd(&a.fillR[r], 1);
      a.eR[pr] = e; a.othR[pr] = c;
      int pc = a.startC[c] + atomicAdd(&a.fillC[c], 1);
      a.eC[pc] = e; a.othC[pc] = r;
    }
    for (int t = gtid; t < kN * 16; t += gsz) {
      int i = t >> 4, jj = t & 15;
      float s = 0.f;
#pragma unroll
      for (int c = 0; c < 16; c++) s += a.hC[(size_t)i * 16 + c] * a.left_w[jj * 16 + c];
      a.lx[t] = s;
    }
  } break;
  case 4: {  // edge_conf + gram2(Va)
    for (int e = gtid; e < kE; e += gsz) {
      float p0 = a.conf_p[0], p1 = a.conf_p[1], p2 = a.conf_p[2];
      float m = fmaxf(p0, fmaxf(p1, p2));
      float e0 = expf(p0 - m), e1 = expf(p1 - m), e2 = expf(p2 - m);
      float inv = 1.f / (e0 + e1 + e2);
      float w0 = e0 * inv, w1 = e1 * inv, w2 = e2 * inv;
      const float* aa = a.lx + (size_t)a.row[e] * 16;
      const float* bb = a.lx + (size_t)a.col[e] * 16;
      float s = 0.f;
#pragma unroll
      for (int c = 0; c < 16; c++) s += fmaxf(aa[c] + bb[c], 0.f) * a.att_w[c];
      float cf = 1.f / (1.f + expf(-s));
      a.conf[e] = cf * w0 + a.ci[e] * w1 + a.ci[(size_t)kE + e] * w2;
    }
    for (int part = bid; part < GRAM_PARTS; part += nb)
      gram2_dev(a.Va, a.hC, a.P, part, smem);
  } break;
  case 5: reduce_dev(a, gtid, gsz); break;
  case 6: {  // block0 inverse(1,0); others spmm(aw)
    if (bid == 0) inverse_dev(a.G, a.Gi, 1.0f, 0.0f, nullptr, nullptr, nullptr, smem);
    else spmm_dev(a.aw, nullptr, nullptr, nullptr, nullptr,
                  a.startR, a.eR, a.othR, a.Va, a.T,
                  (bid - 1) * 4 + (tid >> 6), (nb - 1) * 4);
  } break;
  case 7: outf_dev(a, a.T, nullptr, a.Ua, gtid, gsz); break;
  case 8: {  // edge_score + hist1
    for (int e = gtid; e < kE; e += gsz) {
      const float4* av4 = reinterpret_cast<const float4*>(Ma + (size_t)a.row[e] * 64);
      const float4* bv4 = reinterpret_cast<const float4*>(Mb + (size_t)a.col[e] * 64);
      float s = 0.f;
#pragma unroll
      for (int q = 0; q < 16; q++) {
        float4 av = av4[q], bv = bv4[q];
        s += av.x * bv.x + av.y * bv.y + av.z * bv.z + av.w * bv.w;
      }
      float sc = a.ew[e] - s;
      a.score[e] = sc;
      unsigned u = __float_as_uint(sc * sc);
      atomicAdd(&a.hist1[u >> 16], 1);
    }
  } break;
  case 9: {  // block0 scan1; others gram2(Moth)
    if (bid == 0) scan_dev(a.hist1, a.hist1, 1, a.sel, (int*)smem);
    else for (int part = bid - 1; part < GRAM_PARTS; part += nb - 1)
      gram2_dev(Moth, a.hC, a.P, part, smem);
  } break;
  case 10: {  // reduce + hist2
    reduce_dev(a, gtid, gsz);
    for (int e = gtid; e < kE; e += gsz) {
      float sc = a.score[e];
      unsigned u = __float_as_uint(sc * sc);
      int top = (int)(u >> 16);
      if (top == a.sel->bin1[0]) atomicAdd(&a.h2a[u & 0xFFFF], 1);
      if (top == a.sel->bin1[1]) atomicAdd(&a.h2b[u & 0xFFFF], 1);
    }
  } break;
  case 11: {  // block0 scan2; block1 inverse(1.1,1)+Gp/Hp
    if (bid == 0) scan_dev(a.h2a, a.h2b, 2, a.sel, (int*)smem);
    else if (bid == 1) inverse_dev(a.G, a.Gi, 1.1f, 1.0f, a.hTX, a.Gp, a.Hp, smem);
  } break;
  case 12: {  // spmm with on-the-fly SS
    if (up) spmm_dev(nullptr, a.score, a.conf, a.sel, a.b_param,
                     a.startR, a.eR, a.othR, Vcur, a.T, bid * 4 + (tid >> 6), nb * 4);
    else    spmm_dev(nullptr, a.score, a.conf, a.sel, a.b_param,
                     a.startC, a.eC, a.othC, Ucur, a.T, bid * 4 + (tid >> 6), nb * 4);
  } break;
  case 13: outf_dev(a, a.T, Xcur, Xout, gtid, gsz); break;
  case 14: {  // gram2(final Vcur) ; uv_at(4): Vcur=Va... (j passed = 4)
    for (int part = bid; part < GRAM_PARTS; part += nb)
      gram2_dev(Vcur, a.hC, a.P, part, smem);
  } break;
  case 15: reduce_dev(a, gtid, gsz); break;
  case 16: {  // final_out
    float* sh = smem;
    float* sW = smem + 1024;
    for (int q = tid; q < 1024; q += 256) sh[q] = a.hTX[q];
    sW[tid] = a.Wm[tid & 255];
    __syncthreads();
    for (int i = gtid; i < kN; i += gsz) {
      const float* u = Ucur + (size_t)i * 64;
      float pre[16];
#pragma unroll
      for (int c = 0; c < 16; c++) {
        float s = 0.f;
#pragma unroll
        for (int k = 0; k < 64; k++) s += u[k] * sh[c * 64 + k];
        pre[c] = 0.9f * s + 0.1f * a.hC[(size_t)i * 16 + c];
      }
#pragma unroll
      for (int jj = 0; jj < 16; jj++) {
        float o = 0.f;
#pragma unroll
        for (int c = 0; c < 16; c++) o += pre[c] * sW[c * 16 + jj];
        a.out[(size_t)i * 16 + jj] = o;
      }
    }
  } break;
  }
}

__global__ __launch_bounds__(256, 4) void mega(MegaArgs a)
{
  cg::grid_group grid = cg::this_grid();
  __shared__ __align__(16) float smem[8704];
  for (int p = 0; p <= 7; p++) {
    run_phase(a, p, 0, smem);
    __threadfence(); grid.sync();
  }
  for (int j = 0; j < 4; j++) {
    for (int p = 8; p <= 13; p++) {
      run_phase(a, p, j, smem);
      __threadfence(); grid.sync();
    }
  }
  run_phase(a, 14, 4, smem);
  __threadfence(); grid.sync();
  run_phase(a, 15, 4, smem);
  __threadfence(); grid.sync();
  run_phase(a, 16, 4, smem);
}

// fallback: one phase per launch (kernel boundary = grid sync)
__global__ __launch_bounds__(256, 4) void mega_phase(MegaArgs a, int phase, int j)
{
  __shared__ __align__(16) float smem[8704];
  run_phase(a, phase, j, smem);
}

extern "C" void kernel_launch(void* const* d_in, const int* in_sizes, int n_in,
                              void* d_out, int out_size, void* d_ws, size_t ws_size,
                              hipStream_t stream)
{
  const float* x       = (const float*)d_in[0];
  const int*   eidx    = (const int*)d_in[1];
  const float* ew      = (const float*)d_in[2];
  const float* aw      = (const float*)d_in[3];
  const float* connect = (const float*)d_in[4];
  const float* ci      = (const float*)d_in[5];
  const float* lin1_w  = (const float*)d_in[6];
  const float* lin1_b  = (const float*)d_in[7];
  const float* lin2_w  = (const float*)d_in[8];
  const float* lin2_b  = (const float*)d_in[9];
  const float* lin_a_w = (const float*)d_in[10];
  const float* lin_a_b = (const float*)d_in[11];
  const float* lin_n_w = (const float*)d_in[12];
  const float* lin_n_b = (const float*)d_in[13];
  const float* left_w  = (const float*)d_in[14];
  const float* att_w   = (const float*)d_in[15];
  const float* v_w     = (const float*)d_in[16];
  const float* v_b     = (const float*)d_in[17];
  const float* Wm      = (const float*)d_in[18];
  const float* conf_p  = (const float*)d_in[19];
  const float* b_param = (const float*)d_in[20];
  const int* row = eidx;
  const int* col = eidx + kE;
  float* out = (float*)d_out;

  char* base = (char*)d_ws;
  size_t off = 0;
  auto alloc = [&](size_t bytes) -> void* {
    void* p = base + off;
    off += bytes;
    off = (off + 255) & ~(size_t)255;
    return p;
  };
  float* raw   = (float*)alloc((size_t)kN * kNH * 4);
  float* h16   = (float*)alloc((size_t)kN * kC * 4);
  float* hC    = (float*)alloc((size_t)kN * kC * 4);
  float* nei   = (float*)alloc((size_t)kN * kC * 4);
  float* lx    = (float*)alloc((size_t)kN * kC * 4);
  int*   yhat  = (int*)alloc((size_t)kN * 4);
  float* conf  = (float*)alloc((size_t)kE * 4);
  float* Va    = (float*)alloc((size_t)kN * kK * 4);
  float* Vb    = (float*)alloc((size_t)kN * kK * 4);
  float* Ua    = (float*)alloc((size_t)kN * kK * 4);
  float* Ub    = (float*)alloc((size_t)kN * kK * 4);
  float* T     = (float*)alloc((size_t)kN * kK * 4);
  float* score = (float*)alloc((size_t)kE * 4);
  float* G     = (float*)alloc(64 * 64 * 4);
  float* Gi    = (float*)alloc(64 * 64 * 4);
  float* Gp    = (float*)alloc(64 * 64 * 4);
  float* hTX   = (float*)alloc(kC * kK * 4);
  float* Hp    = (float*)alloc(kC * kK * 4);
  int* hist1   = (int*)alloc(65536 * 4);
  int* h2a     = (int*)alloc(65536 * 4);
  int* h2b     = (int*)alloc(65536 * 4);
  SelState* sel = (SelState*)alloc(sizeof(SelState));
  int* cntR    = (int*)alloc((size_t)kN * 4);
  int* cntC    = (int*)alloc((size_t)kN * 4);
  int* fillR   = (int*)alloc((size_t)kN * 4);
  int* fillC   = (int*)alloc((size_t)kN * 4);
  int* startR  = (int*)alloc((size_t)(kN + 1) * 4);
  int* startC  = (int*)alloc((size_t)(kN + 1) * 4);
  int* eR      = (int*)alloc((size_t)kE * 4);
  int* eC      = (int*)alloc((size_t)kE * 4);
  int* othR    = (int*)alloc((size_t)kE * 4);
  int* othC    = (int*)alloc((size_t)kE * 4);
  float* P     = (float*)alloc((size_t)GRAM_PARTS * 5120 * 4);
  const int KpC = 10016, KpX = 512, KpV = 256;
  ushort* BcH = (ushort*)alloc((size_t)256 * KpC * 2);
  ushort* BcL = (ushort*)alloc((size_t)256 * KpC * 2);
  ushort* BxH = (ushort*)alloc((size_t)256 * KpX * 2);
  ushort* BxL = (ushort*)alloc((size_t)256 * KpX * 2);
  ushort* BvH = (ushort*)alloc((size_t)64 * KpV * 2);
  ushort* BvL = (ushort*)alloc((size_t)64 * KpV * 2);
  float* Pbig  = (float*)alloc((size_t)6 * kN * kNH * 4);

  // ---- pre-split weights ----
  split_bf<<<(256 * KpC + 255) / 256, 256, 0, stream>>>(lin_a_w, BcH, BcL, 256, 10000, KpC);
  split_bf<<<(256 * KpX + 255) / 256, 256, 0, stream>>>(lin1_w, BxH, BxL, 256, 500, KpX);
  split_bf<<<(64 * KpV + 255) / 256, 256, 0, stream>>>(v_w, BvH, BvL, 64, 256, KpV);

  // ---- dense front-end (MFMA) ----
  gemm_v3<256, false><<<dim3(157, 1, 6), 256, 0, stream>>>(
      connect, BcH, BcL, nullptr, Pbig, kN, 10000, KpC, 1696, kNH);
  gemm_v3<256, true><<<dim3(157, 1, 1), 256, 0, stream>>>(
      x, BxH, BxL, nullptr, raw, kN, 500, KpX, 512, kNH);
  reduce_raw<<<(kN * kNH / 4 + 255) / 256, 256, 0, stream>>>(
      (const float4*)Pbig, (const float4*)raw, lin_a_b, lin1_b, (float4*)raw);
  gemm_v3<64, true><<<dim3(157, 1, 1), 256, 0, stream>>>(
      raw, BvH, BvL, v_b, Va, kN, 256, KpV, 256, kK);

  // ---- mega args ----
  MegaArgs ma;
  ma.raw = raw; ma.lin2_w = lin2_w; ma.lin2_b = lin2_b;
  ma.row = row; ma.col = col; ma.aw = aw; ma.ew = ew;
  ma.lnw = lin_n_w; ma.lnb = lin_n_b; ma.left_w = left_w; ma.att_w = att_w;
  ma.ci = ci; ma.conf_p = conf_p; ma.b_param = b_param; ma.Wm = Wm;
  ma.h16 = h16; ma.yhat = yhat; ma.nei = nei; ma.hC = hC; ma.lx = lx; ma.conf = conf;
  ma.cntR = cntR; ma.cntC = cntC; ma.fillR = fillR; ma.fillC = fillC;
  ma.startR = startR; ma.startC = startC;
  ma.eR = eR; ma.eC = eC; ma.othR = othR; ma.othC = othC;
  ma.Va = Va; ma.Vb = Vb; ma.Ua = Ua; ma.Ub = Ub; ma.T = T;
  ma.score = score; ma.G = G; ma.Gi = Gi; ma.Gp = Gp; ma.hTX = hTX; ma.Hp = Hp;
  ma.hist1 = hist1; ma.h2a = h2a; ma.h2b = h2b;
  ma.P = P; ma.sel = sel; ma.out = out;

  // ---- cooperative launch with occupancy-clamped grid; checked; fallback ----
  int dev = 0;
  (void)hipGetDevice(&dev);
  int numCU = 0;
  (void)hipDeviceGetAttribute(&numCU, hipDeviceAttributeMultiprocessorCount, dev);
  int maxPerCU = 0;
  hipError_t oe = hipOccupancyMaxActiveBlocksPerMultiprocessor(
      &maxPerCU, (const void*)mega, 256, 0);
  int grid = 768;
  if (oe == hipSuccess && numCU > 0 && maxPerCU > 0) {
    long cap = (long)maxPerCU * numCU;
    if (cap < grid) grid = (int)cap;
  }
  if (grid < 2) grid = 2;

  void* args[] = { &ma };
  hipError_t err = hipLaunchCooperativeKernel((const void*)mega, dim3(grid), dim3(256),
                                              args, 0, stream);
  if (err != hipSuccess) {
    // fallback: identical phases, one launch each (kernel boundary = sync)
    for (int p = 0; p <= 7; p++) mega_phase<<<640, 256, 0, stream>>>(ma, p, 0);
    for (int j = 0; j < 4; j++)
      for (int p = 8; p <= 13; p++) mega_phase<<<640, 256, 0, stream>>>(ma, p, j);
    mega_phase<<<640, 256, 0, stream>>>(ma, 14, 4);
    mega_phase<<<640, 256, 0, stream>>>(ma, 15, 4);
    mega_phase<<<640, 256, 0, stream>>>(ma, 16, 4);
  }
}

// Round 10
// 2083.542 us; speedup vs baseline: 2.8093x; 2.8093x over previous
//
#include <hip/hip_runtime.h>
#include <cstddef>
#include <cstdint>

// Round 10: R9's phase pipeline with KERNEL BOUNDARIES as grid sync
// (R9 measured coop grid.sync at ~200us each -> 7ms of idle; launch
// boundary is ~15-25us). Phase count compressed: 6 prologue + 6/iter + 3.
// 40 dispatches total. GEMM front-end unchanged.

constexpr int kN  = 10000;
constexpr int kE  = 320000;
constexpr int kNH = 256;
constexpr int kC  = 16;
constexpr int kK  = 64;
constexpr int GRAM_PARTS = 256;   // 40-row chunks
constexpr int PHASE_BLOCKS = 768;

struct SelState {
  int bin1[2]; int rem1[2];
  float thr_base;
};

typedef short bf16x8 __attribute__((ext_vector_type(8)));
typedef float f32x4 __attribute__((ext_vector_type(4)));
typedef ushort ushort8 __attribute__((ext_vector_type(8)));

__device__ __forceinline__ ushort f2bf(float x) {
  unsigned u = __float_as_uint(x);
  unsigned r = (u + 0x7fffu + ((u >> 16) & 1u)) >> 16;   // RNE
  return (ushort)r;
}
__device__ __forceinline__ float bf2f(ushort h) {
  return __uint_as_float((unsigned)h << 16);
}
__device__ __forceinline__ int swz(int row, int byteInRow) {
  int chunk = (byteInRow >> 4) ^ ((row >> 1) & 3);
  return row * 64 + (chunk << 4) + (byteInRow & 15);
}

__global__ void split_bf(const float* __restrict__ B, ushort* __restrict__ hi,
                         ushort* __restrict__ lo, int N2, int K, int Kp)
{
  int t = blockIdx.x * 256 + threadIdx.x;
  if (t >= N2 * Kp) return;
  int r = t / Kp, c = t % Kp;
  float v = (c < K) ? B[(size_t)r * K + c] : 0.f;
  ushort h = f2bf(v);
  hi[t] = h;
  lo[t] = f2bf(v - bf2f(h));
}

// ===== MFMA GEMM (unchanged from R7) =====
template<int BN, bool ALO>
__global__ __launch_bounds__(256) void gemm_v3(
    const float* __restrict__ A, const ushort* __restrict__ Bhg,
    const ushort* __restrict__ Blg, const float* __restrict__ bias,
    float* __restrict__ out, int M, int K, int Kp, int KR, int outStride)
{
  __shared__ __align__(16) char sAh[64 * 64];
  __shared__ __align__(16) char sAl[ALO ? 64 * 64 : 16];
  __shared__ __align__(16) char sBh[BN * 64];
  __shared__ __align__(16) char sBl[BN * 64];
  const int t = threadIdx.x;
  const int lane = t & 63, w = t >> 6;
  const int bm = blockIdx.x * 64;
  const int k0 = blockIdx.z * KR;
  const int kend = min(K, k0 + KR);
  out += (size_t)blockIdx.z * M * outStride;
  constexpr int WN = BN / 64;
  constexpr int RB = WN;
  const int wc = (w % WN) * 64;
  const int wr = (w / WN) * (RB * 16);
  const int l15 = lane & 15;
  const int lByte = (lane >> 4) * 16;
  const int ar = t >> 2, ac = t & 3;

  f32x4 acc[RB][4] = {};
  for (int kt = k0; kt < kend; kt += 32) {
    {
      int gr = bm + ar, gk = kt + ac * 8;
      float v[8];
      if (gr < M && gk + 8 <= kend) {
        float4 v0 = *reinterpret_cast<const float4*>(A + (size_t)gr * K + gk);
        float4 v1 = *reinterpret_cast<const float4*>(A + (size_t)gr * K + gk + 4);
        v[0] = v0.x; v[1] = v0.y; v[2] = v0.z; v[3] = v0.w;
        v[4] = v1.x; v[5] = v1.y; v[6] = v1.z; v[7] = v1.w;
      } else {
#pragma unroll
        for (int q = 0; q < 8; q++)
          v[q] = (gr < M && gk + q < kend) ? A[(size_t)gr * K + gk + q] : 0.f;
      }
      ushort8 h8, l8;
#pragma unroll
      for (int q = 0; q < 8; q++) {
        ushort h = f2bf(v[q]); h8[q] = h;
        if (ALO) l8[q] = f2bf(v[q] - bf2f(h));
      }
      *reinterpret_cast<ushort8*>(sAh + swz(ar, ac * 16)) = h8;
      if (ALO) *reinterpret_cast<ushort8*>(sAl + swz(ar, ac * 16)) = l8;
    }
#pragma unroll
    for (int i2 = 0; i2 < BN / 64; i2++) {
      int idx = t + i2 * 256;
      int r = idx >> 2, c = idx & 3;
      size_t gb = (size_t)r * Kp + kt + c * 8;
      ushort8 hv = *reinterpret_cast<const ushort8*>(Bhg + gb);
      ushort8 lv = *reinterpret_cast<const ushort8*>(Blg + gb);
      *reinterpret_cast<ushort8*>(sBh + swz(r, c * 16)) = hv;
      *reinterpret_cast<ushort8*>(sBl + swz(r, c * 16)) = lv;
    }
    __syncthreads();
    bf16x8 bh[4], bl[4];
#pragma unroll
    for (int nbq = 0; nbq < 4; nbq++) {
      int rr = wc + nbq * 16 + l15;
      bh[nbq] = *reinterpret_cast<const bf16x8*>(sBh + swz(rr, lByte));
      bl[nbq] = *reinterpret_cast<const bf16x8*>(sBl + swz(rr, lByte));
    }
#pragma unroll
    for (int rb = 0; rb < RB; rb++) {
      int rr = wr + rb * 16 + l15;
      bf16x8 ah = *reinterpret_cast<const bf16x8*>(sAh + swz(rr, lByte));
#pragma unroll
      for (int nbq = 0; nbq < 4; nbq++) {
        acc[rb][nbq] = __builtin_amdgcn_mfma_f32_16x16x32_bf16(ah, bh[nbq], acc[rb][nbq], 0, 0, 0);
        acc[rb][nbq] = __builtin_amdgcn_mfma_f32_16x16x32_bf16(ah, bl[nbq], acc[rb][nbq], 0, 0, 0);
      }
      if (ALO) {
        bf16x8 al = *reinterpret_cast<const bf16x8*>(sAl + swz(rr, lByte));
#pragma unroll
        for (int nbq = 0; nbq < 4; nbq++)
          acc[rb][nbq] = __builtin_amdgcn_mfma_f32_16x16x32_bf16(al, bh[nbq], acc[rb][nbq], 0, 0, 0);
      }
    }
    __syncthreads();
  }
#pragma unroll
  for (int rb = 0; rb < RB; rb++) {
#pragma unroll
    for (int nbq = 0; nbq < 4; nbq++) {
      int colg = wc + nbq * 16 + l15;
      float bv = bias ? bias[colg] : 0.f;
#pragma unroll
      for (int jj = 0; jj < 4; jj++) {
        int rowg = bm + wr + rb * 16 + (lane >> 4) * 4 + jj;
        if (rowg < M) out[(size_t)rowg * outStride + colg] = acc[rb][nbq][jj] + bv;
      }
    }
  }
}

// raw = relu(...); ALSO zeroes cnt/fill/nei for the phase pipeline.
__global__ void reduce_raw(const float4* __restrict__ Pa, const float4* px,
                           const float* __restrict__ ba, const float* __restrict__ b1,
                           float4* rawOut, int* cntR, int* cntC, int* fillR,
                           int* fillC, float* nei)
{
  int t = blockIdx.x * 256 + threadIdx.x;
  if (t < kN) { cntR[t] = 0; cntC[t] = 0; fillR[t] = 0; fillC[t] = 0; }
  if (t < kN * kC) nei[t] = 0.f;
  if (t >= kN * kNH / 4) return;
  const int sl = kN * kNH / 4;
  float4 s = Pa[t];
#pragma unroll
  for (int p = 1; p < 6; p++) {
    float4 q = Pa[t + (size_t)p * sl];
    s.x += q.x; s.y += q.y; s.z += q.z; s.w += q.w;
  }
  float4 pxv = px[t];
  int c4 = t & 63;
  float4 vba = reinterpret_cast<const float4*>(ba)[c4];
  float4 vb1 = reinterpret_cast<const float4*>(b1)[c4];
  float4 r;
  r.x = fmaxf(0.5f * (s.x + vba.x) + 0.5f * (pxv.x + vb1.x), 0.f);
  r.y = fmaxf(0.5f * (s.y + vba.y) + 0.5f * (pxv.y + vb1.y), 0.f);
  r.z = fmaxf(0.5f * (s.z + vba.z) + 0.5f * (pxv.z + vb1.z), 0.f);
  r.w = fmaxf(0.5f * (s.w + vba.w) + 0.5f * (pxv.w + vb1.w), 0.f);
  rawOut[t] = r;
}

// =================== phase args ===================
struct MegaArgs {
  const float* raw;
  const float* lin2_w; const float* lin2_b;
  const int* row; const int* col;
  const float* aw; const float* ew;
  const float* lnw; const float* lnb;
  const float* left_w; const float* att_w;
  const float* ci; const float* conf_p; const float* b_param;
  const float* Wm;
  float* h16; int* yhat; float* nei; float* hC; float* lx; float* conf;
  int* cntR; int* cntC; int* fillR; int* fillC; int* startR; int* startC;
  int* eR; int* eC; int* othR; int* othC;
  float* Va; float* Vb; float* Ua; float* Ub; float* T;
  float* score; float* G; float* Gi; float* Gp; float* hTX; float* Hp;
  int* hist1; int* h2a; int* h2b;
  float* P;
  SelState* sel;
  float* out;
};

// U/V ping-pong state entering iteration j (verified via R9 pass; j=4 -> Ua,Va)
__device__ __forceinline__ void uv_at(const MegaArgs& a, int j,
                                      float*& Ucur, float*& Unxt,
                                      float*& Vcur, float*& Vnxt)
{
  int uU = (j >= 1) + (j >= 3);
  int uV = (j >= 2) + (j >= 4);
  Ucur = (uU & 1) ? a.Ub : a.Ua; Unxt = (uU & 1) ? a.Ua : a.Ub;
  Vcur = (uV & 1) ? a.Vb : a.Va; Vnxt = (uV & 1) ? a.Va : a.Vb;
}

// ---- phase helpers (bodies verbatim from R9, which passed) ----
__device__ void gram2_dev(const float* M, const float* hc, float* P, int b, float* shm)
{
  float* sM = shm;
  float* sH = shm + 512;
  const int t = threadIdx.x;
  const int aG = t >> 2, cG0 = (t & 3) * 16;
  const int aH = t >> 4, cH0 = (t & 15) * 4;
  float accG[16]; float accH[4];
#pragma unroll
  for (int q = 0; q < 16; q++) accG[q] = 0.f;
#pragma unroll
  for (int q = 0; q < 4; q++) accH[q] = 0.f;
  int r0 = b * 40, r1 = min(kN, r0 + 40);
  for (int rb = r0; rb < r1; rb += 8) {
    int nb2 = min(8, r1 - rb);
    __syncthreads();
    for (int q = t; q < nb2 * 64; q += 256) sM[q] = M[(size_t)rb * 64 + q];
    for (int q = t; q < nb2 * 16; q += 256) sH[q] = hc[(size_t)rb * 16 + q];
    __syncthreads();
    for (int r = 0; r < nb2; r++) {
      float avG = sM[r * 64 + aG];
      const float* sbG = &sM[r * 64 + cG0];
#pragma unroll
      for (int q = 0; q < 16; q++) accG[q] += avG * sbG[q];
      float avH = sH[r * 16 + aH];
      const float* sbH = &sM[r * 64 + cH0];
#pragma unroll
      for (int q = 0; q < 4; q++) accH[q] += avH * sbH[q];
    }
  }
  float* p1 = P + (size_t)b * 5120 + aG * 64 + cG0;
#pragma unroll
  for (int q = 0; q < 16; q++) p1[q] = accG[q];
  float* p2 = P + (size_t)b * 5120 + 4096 + aH * 64 + cH0;
#pragma unroll
  for (int q = 0; q < 4; q++) p2[q] = accH[q];
}

__device__ void inverse_dev(const float* G, float* Gi, float alpha, float beta,
                            const float* hTX, float* Gp, float* Hp, float* shm)
{
  float* A = shm;
  float* prow = shm + 8448;
  float* fcol = shm + 8576;
  const int t = threadIdx.x;
  for (int q = t; q < 64 * 128; q += 256) {
    int r = q >> 7, c = q & 127;
    float v;
    if (c < 64) v = alpha * G[r * 64 + c] + ((c == r) ? beta : 0.f);
    else        v = (c - 64 == r) ? 1.f : 0.f;
    A[r * 132 + c] = v;
  }
  __syncthreads();
  const int i  = t >> 2;
  const int c0 = (t & 3) * 32;
  for (int k = 0; k < 64; k++) {
    if (t < 128) prow[t] = A[k * 132 + t];
    else if (t < 192) fcol[t - 128] = A[(t - 128) * 132 + k];
    __syncthreads();
    float pinv = 1.f / prow[k];
    float f = fcol[i];
    float4* Ar = reinterpret_cast<float4*>(&A[i * 132 + c0]);
    const float4* pr = reinterpret_cast<const float4*>(&prow[c0]);
    if (i == k) {
#pragma unroll
      for (int q = 0; q < 8; q++) {
        float4 p = pr[q];
        p.x *= pinv; p.y *= pinv; p.z *= pinv; p.w *= pinv;
        Ar[q] = p;
      }
    } else {
#pragma unroll
      for (int q = 0; q < 8; q++) {
        float4 p = pr[q]; float4 av = Ar[q];
        av.x -= f * (p.x * pinv); av.y -= f * (p.y * pinv);
        av.z -= f * (p.z * pinv); av.w -= f * (p.w * pinv);
        Ar[q] = av;
      }
    }
    __syncthreads();
  }
  for (int q = t; q < 4096; q += 256) Gi[q] = A[(q >> 6) * 132 + 64 + (q & 63)];
  if (Gp) {
    for (int q = t; q < 4096; q += 256) {
      int r = q >> 6, k = q & 63;
      float s = 0.f;
#pragma unroll 8
      for (int jj = 0; jj < 64; jj++) s += G[r * 64 + jj] * A[jj * 132 + 64 + k];
      Gp[q] = s;
    }
    for (int q = t; q < 1024; q += 256) {
      int c = q >> 6, k = q & 63;
      float s = 0.f;
#pragma unroll 8
      for (int jj = 0; jj < 64; jj++) s += hTX[c * 64 + jj] * A[jj * 132 + 64 + k];
      Hp[q] = 0.1f * s;  // EPS
    }
  }
}

__device__ void scan_dev(const int* h0, const int* h1, int stage, SelState* sel, int* shm)
{
  const int t = threadIdx.x;
  int* part = shm;
  int* fbs  = shm + 256;
  float* qsh = (float*)(shm + 258);
  for (int tgt = 0; tgt < 2; tgt++) {
    const int* H = tgt ? h1 : h0;
    const int4* H4 = reinterpret_cast<const int4*>(H + t * 256);
    int R = (stage == 1) ? (tgt ? (3 * kE / 4) : (kE / 4)) : sel->rem1[tgt];
    int lsum = 0;
    for (int b = 0; b < 64; b++) { int4 v = H4[b]; lsum += v.x + v.y + v.z + v.w; }
    part[t] = lsum;
    __syncthreads();
    for (int off = 1; off < 256; off <<= 1) {
      int v = part[t];
      int u = (t >= off) ? part[t - off] : 0;
      __syncthreads();
      part[t] = v + u;
      __syncthreads();
    }
    int cum = part[t] - lsum;
    int fb = -1, fr = 0;
    for (int b = 0; b < 64; b++) {
      int4 v = H4[b];
      int bb = t * 256 + b * 4;
      if (fb < 0 && R >= cum && R < cum + v.x) { fb = bb;     fr = R - cum; } cum += v.x;
      if (fb < 0 && R >= cum && R < cum + v.y) { fb = bb + 1; fr = R - cum; } cum += v.y;
      if (fb < 0 && R >= cum && R < cum + v.z) { fb = bb + 2; fr = R - cum; } cum += v.z;
      if (fb < 0 && R >= cum && R < cum + v.w) { fb = bb + 3; fr = R - cum; } cum += v.w;
    }
    if (fb >= 0) {
      fbs[tgt] = fb;
      if (stage == 1) { sel->bin1[tgt] = fb; sel->rem1[tgt] = fr; }
    }
    __syncthreads();
    if (stage == 2 && t == 0) {
      unsigned u = ((unsigned)sel->bin1[tgt] << 16) | (unsigned)fbs[tgt];
      qsh[tgt] = __uint_as_float(u);
    }
    __syncthreads();
  }
  if (stage == 2 && t == 0) {
    float q1 = qsh[0], q3 = qsh[1];
    sel->thr_base = q3 + 1.5f * (q3 - q1);
  }
}

__device__ void spmm_dev(const float* vals, const float* score, const float* conf,
                         const SelState* sel, const float* bp,
                         const int* start, const int* eids, const int* oth,
                         const float* Msrc, float* T, int wid0, int wstride)
{
  int lane = threadIdx.x & 63;
  float tb = 0.f, bp0 = 0.f;
  if (!vals) { tb = sel->thr_base; bp0 = bp[0]; }
  for (int wid = wid0; wid < kN; wid += wstride) {
    int p = start[wid], pend = start[wid + 1];
    float acc = 0.f;
    for (; p + 4 <= pend; p += 4) {
      int e0 = eids[p], e1 = eids[p + 1], e2 = eids[p + 2], e3 = eids[p + 3];
      int o0 = oth[p], o1 = oth[p + 1], o2 = oth[p + 2], o3 = oth[p + 3];
      float m0 = Msrc[(size_t)o0 * 64 + lane];
      float m1 = Msrc[(size_t)o1 * 64 + lane];
      float m2 = Msrc[(size_t)o2 * 64 + lane];
      float m3 = Msrc[(size_t)o3 * 64 + lane];
      float v0, v1, v2, v3;
      if (vals) { v0 = vals[e0]; v1 = vals[e1]; v2 = vals[e2]; v3 = vals[e3]; }
      else {
        float s0 = score[e0], s1 = score[e1], s2 = score[e2], s3 = score[e3];
        v0 = (s0 * s0 < tb * conf[e0]) ? (s0 + bp0) : 0.f;
        v1 = (s1 * s1 < tb * conf[e1]) ? (s1 + bp0) : 0.f;
        v2 = (s2 * s2 < tb * conf[e2]) ? (s2 + bp0) : 0.f;
        v3 = (s3 * s3 < tb * conf[e3]) ? (s3 + bp0) : 0.f;
      }
      acc += v0 * m0 + v1 * m1 + v2 * m2 + v3 * m3;
    }
    for (; p < pend; ++p) {
      int e = eids[p];
      float v;
      if (vals) v = vals[e];
      else { float sc = score[e]; v = (sc * sc < tb * conf[e]) ? (sc + bp0) : 0.f; }
      acc += v * Msrc[(size_t)oth[p] * 64 + lane];
    }
    T[(size_t)wid * 64 + lane] = acc;
  }
}

__device__ void outf_dev(const MegaArgs& a, const float* T, const float* X,
                         float* Out, int gtid, int gsz)
{
  for (int i = gtid; i < 65536; i += gsz) { a.hist1[i] = 0; a.h2a[i] = 0; a.h2b[i] = 0; }
  for (int t = gtid; t < kN * 16; t += gsz) {
    int i = t >> 4, kq = t & 15;
    const float* ti = T + (size_t)i * 64;
    const float4* G4 = reinterpret_cast<const float4*>(a.Gi);
    float4 s = make_float4(0.f, 0.f, 0.f, 0.f);
#pragma unroll 8
    for (int jj = 0; jj < 64; jj++) {
      float tv = ti[jj];
      float4 g = G4[jj * 16 + kq];
      s.x += tv * g.x; s.y += tv * g.y; s.z += tv * g.z; s.w += tv * g.w;
    }
    if (X) {
      const float* xi = X + (size_t)i * 64;
      const float4* Gp4 = reinterpret_cast<const float4*>(a.Gp);
      float4 s2 = make_float4(0.f, 0.f, 0.f, 0.f);
#pragma unroll 8
      for (int jj = 0; jj < 64; jj++) {
        float xv = xi[jj];
        float4 g = Gp4[jj * 16 + kq];
        s2.x += xv * g.x; s2.y += xv * g.y; s2.z += xv * g.z; s2.w += xv * g.w;
      }
      s.x += s2.x; s.y += s2.y; s.z += s2.z; s.w += s2.w;
      const float4* Hp4 = reinterpret_cast<const float4*>(a.Hp);
      float4 s3 = make_float4(0.f, 0.f, 0.f, 0.f);
#pragma unroll
      for (int c = 0; c < 16; c++) {
        float hv = a.hC[(size_t)i * 16 + c];
        float4 g = Hp4[c * 16 + kq];
        s3.x += hv * g.x; s3.y += hv * g.y; s3.z += hv * g.z; s3.w += hv * g.w;
      }
      s.x += s3.x; s.y += s3.y; s.z += s3.z; s.w += s3.w;
    }
    *reinterpret_cast<float4*>(Out + (size_t)i * 64 + kq * 4) = s;
  }
}

__device__ void reduce_dev(const MegaArgs& a, int gtid, int gsz)
{
  for (int c = gtid; c < 5120; c += gsz) {
    float s = 0.f;
    for (int p = 0; p < GRAM_PARTS; p++) s += a.P[(size_t)p * 5120 + c];
    if (c < 4096) a.G[c] = s;
    else a.hTX[c - 4096] = s;
  }
}

// ---- compressed phase pipeline: one launch per phase ----
//  0: h16+argmax
//  1: csr_count + scatter_nei ; gram2(Va, dummy-hc)   [init hTX is dead]
//  2: b0: csr scans ; b>=1: norm_xn_h then reduce
//  3: b0: inverse(1,0) ; b>=1: csr_fill then lx
//  4: edge_conf ; spmm(aw, CSR-R)
//  5: outf -> Ua  (+zero hists)
//  6..11 (per iter j): score+hist1 | scan1||gram2 | reduce+hist2 |
//                      scan2||inverse | spmm(SS) | outf
//  12: gram2(V final) ; 13: reduce ; 14: final_out
__global__ __launch_bounds__(256, 4) void mega_phase(MegaArgs a, int phase, int j)
{
  __shared__ __align__(16) float smem[8704];
  const int tid = threadIdx.x;
  const int bid = blockIdx.x;
  const int nb  = gridDim.x;
  const int gtid = bid * 256 + tid;
  const int gsz = nb * 256;
  float *Ucur, *Unxt, *Vcur, *Vnxt;
  uv_at(a, j, Ucur, Unxt, Vcur, Vnxt);
  bool up = ((j & 1) == 0);
  const float* Ma   = up ? Ucur : Vcur;
  const float* Mb   = up ? Vcur : Ucur;
  const float* Moth = up ? Vcur : Ucur;
  const float* Xcur = up ? Ucur : Vcur;
  float* Xout       = up ? Unxt : Vnxt;

  switch (phase) {
  case 0: {  // h16 + argmax
    for (int t = gtid; t < kN * 16; t += gsz) {
      int i = t >> 4, jj = t & 15;
      const float4* av4 = reinterpret_cast<const float4*>(a.raw + (size_t)i * 256);
      const float4* bv4 = reinterpret_cast<const float4*>(a.lin2_w + (size_t)jj * 256);
      float s = a.lin2_b[jj];
#pragma unroll 8
      for (int q = 0; q < 64; q++) {
        float4 av = av4[q], bv = bv4[q];
        s += av.x * bv.x + av.y * bv.y + av.z * bv.z + av.w * bv.w;
      }
      a.h16[t] = s;
      float m = s; int am = jj;
#pragma unroll
      for (int off = 1; off < 16; off <<= 1) {
        float om = __shfl_xor(m, off);
        int oa = __shfl_xor(am, off);
        if (om > m || (om == m && oa < am)) { m = om; am = oa; }
      }
      if (jj == 0) a.yhat[i] = am;
    }
  } break;
  case 1: {  // csr_count + scatter_nei ; gram2(Va) with dummy hc (P2 dead in init)
    for (int e = gtid; e < kE; e += gsz) {
      int r = a.row[e], c = a.col[e];
      atomicAdd(&a.cntR[r], 1);
      atomicAdd(&a.cntC[c], 1);
      atomicAdd(&a.nei[(size_t)r * 16 + a.yhat[c]], a.aw[e]);
    }
    for (int part = bid; part < GRAM_PARTS; part += nb)
      gram2_dev(a.Va, a.Va /*dummy hc: deterministic, result unused*/, a.P, part, smem);
  } break;
  case 2: {  // b0: csr scans ; b>=1: norm + reduce
    if (bid == 0) {
      int* part = (int*)smem;
      for (int pass = 0; pass < 2; ++pass) {
        const int* cnt = pass ? a.cntC : a.cntR;
        int* start = pass ? a.startC : a.startR;
        int bbase = tid * 40;
        int s = 0;
        for (int q = 0; q < 40; q++) { int idx = bbase + q; if (idx < kN) s += cnt[idx]; }
        part[tid] = s;
        __syncthreads();
        for (int off = 1; off < 256; off <<= 1) {
          int v = part[tid];
          int u = (tid >= off) ? part[tid - off] : 0;
          __syncthreads();
          part[tid] = v + u;
          __syncthreads();
        }
        int run = part[tid] - s;
        for (int q = 0; q < 40; q++) {
          int idx = bbase + q;
          if (idx < kN) { start[idx] = run; run += cnt[idx]; }
        }
        if (tid == 255) start[kN] = part[255];
        __syncthreads();
      }
    } else {
      int g2 = (bid - 1) * 256 + tid, s2 = (nb - 1) * 256;
      for (int i = g2; i < kN; i += s2) {
        float nv[16]; float s = 0.f;
#pragma unroll
        for (int c = 0; c < 16; c++) { nv[c] = a.nei[(size_t)i * 16 + c]; s += nv[c]; }
        float inv = (s != 0.f) ? 1.f / s : 0.f;
#pragma unroll
        for (int jj = 0; jj < 16; jj++) {
          float xn = a.lnb[jj];
#pragma unroll
          for (int c = 0; c < 16; c++) xn += (nv[c] * inv) * a.lnw[jj * 16 + c];
          xn = fmaxf(xn, 0.f);
          a.hC[(size_t)i * 16 + jj] = 0.5f * a.h16[(size_t)i * 16 + jj] + 0.5f * xn;
        }
      }
      for (int c = g2; c < 5120; c += s2) {
        float s = 0.f;
        for (int p = 0; p < GRAM_PARTS; p++) s += a.P[(size_t)p * 5120 + c];
        if (c < 4096) a.G[c] = s;
        else a.hTX[c - 4096] = s;   // garbage in init; dead (overwritten in iter 0)
      }
    }
  } break;
  case 3: {  // b0: inverse(1,0) ; b>=1: csr_fill then lx
    if (bid == 0) {
      inverse_dev(a.G, a.Gi, 1.0f, 0.0f, nullptr, nullptr, nullptr, smem);
    } else {
      int g2 = (bid - 1) * 256 + tid, s2 = (nb - 1) * 256;
      for (int e = g2; e < kE; e += s2) {
        int r = a.row[e], c = a.col[e];
        int pr = a.startR[r] + atomicAdd(&a.fillR[r], 1);
        a.eR[pr] = e; a.othR[pr] = c;
        int pc = a.startC[c] + atomicAdd(&a.fillC[c], 1);
        a.eC[pc] = e; a.othC[pc] = r;
      }
      for (int t = g2; t < kN * 16; t += s2) {
        int i = t >> 4, jj = t & 15;
        float s = 0.f;
#pragma unroll
        for (int c = 0; c < 16; c++) s += a.hC[(size_t)i * 16 + c] * a.left_w[jj * 16 + c];
        a.lx[t] = s;
      }
    }
  } break;
  case 4: {  // edge_conf ; spmm(aw)
    for (int e = gtid; e < kE; e += gsz) {
      float p0 = a.conf_p[0], p1 = a.conf_p[1], p2 = a.conf_p[2];
      float m = fmaxf(p0, fmaxf(p1, p2));
      float e0 = expf(p0 - m), e1 = expf(p1 - m), e2 = expf(p2 - m);
      float inv = 1.f / (e0 + e1 + e2);
      float w0 = e0 * inv, w1 = e1 * inv, w2 = e2 * inv;
      const float* aa = a.lx + (size_t)a.row[e] * 16;
      const float* bb = a.lx + (size_t)a.col[e] * 16;
      float s = 0.f;
#pragma unroll
      for (int c = 0; c < 16; c++) s += fmaxf(aa[c] + bb[c], 0.f) * a.att_w[c];
      float cf = 1.f / (1.f + expf(-s));
      a.conf[e] = cf * w0 + a.ci[e] * w1 + a.ci[(size_t)kE + e] * w2;
    }
    spmm_dev(a.aw, nullptr, nullptr, nullptr, nullptr,
             a.startR, a.eR, a.othR, a.Va, a.T, bid * 4 + (tid >> 6), nb * 4);
  } break;
  case 5: outf_dev(a, a.T, nullptr, a.Ua, gtid, gsz); break;
  case 6: {  // edge_score + hist1
    for (int e = gtid; e < kE; e += gsz) {
      const float4* av4 = reinterpret_cast<const float4*>(Ma + (size_t)a.row[e] * 64);
      const float4* bv4 = reinterpret_cast<const float4*>(Mb + (size_t)a.col[e] * 64);
      float s = 0.f;
#pragma unroll
      for (int q = 0; q < 16; q++) {
        float4 av = av4[q], bv = bv4[q];
        s += av.x * bv.x + av.y * bv.y + av.z * bv.z + av.w * bv.w;
      }
      float sc = a.ew[e] - s;
      a.score[e] = sc;
      unsigned u = __float_as_uint(sc * sc);
      atomicAdd(&a.hist1[u >> 16], 1);
    }
  } break;
  case 7: {  // b0: scan1 ; b>=1: gram2(Moth)
    if (bid == 0) scan_dev(a.hist1, a.hist1, 1, a.sel, (int*)smem);
    else for (int part = bid - 1; part < GRAM_PARTS; part += nb - 1)
      gram2_dev(Moth, a.hC, a.P, part, smem);
  } break;
  case 8: {  // reduce + hist2
    reduce_dev(a, gtid, gsz);
    for (int e = gtid; e < kE; e += gsz) {
      float sc = a.score[e];
      unsigned u = __float_as_uint(sc * sc);
      int top = (int)(u >> 16);
      if (top == a.sel->bin1[0]) atomicAdd(&a.h2a[u & 0xFFFF], 1);
      if (top == a.sel->bin1[1]) atomicAdd(&a.h2b[u & 0xFFFF], 1);
    }
  } break;
  case 9: {  // b0: scan2 ; b1: inverse(1.1,1)+Gp/Hp
    if (bid == 0) scan_dev(a.h2a, a.h2b, 2, a.sel, (int*)smem);
    else if (bid == 1) inverse_dev(a.G, a.Gi, 1.1f, 1.0f, a.hTX, a.Gp, a.Hp, smem);
  } break;
  case 10: {  // spmm with on-the-fly SS
    if (up) spmm_dev(nullptr, a.score, a.conf, a.sel, a.b_param,
                     a.startR, a.eR, a.othR, Vcur, a.T, bid * 4 + (tid >> 6), nb * 4);
    else    spmm_dev(nullptr, a.score, a.conf, a.sel, a.b_param,
                     a.startC, a.eC, a.othC, Ucur, a.T, bid * 4 + (tid >> 6), nb * 4);
  } break;
  case 11: outf_dev(a, a.T, Xcur, Xout, gtid, gsz); break;
  case 12: {  // gram2(final V); j passed = 4 -> Vcur = Va
    for (int part = bid; part < GRAM_PARTS; part += nb)
      gram2_dev(Vcur, a.hC, a.P, part, smem);
  } break;
  case 13: reduce_dev(a, gtid, gsz); break;
  case 14: {  // final_out (j=4 -> Ucur = Ua)
    float* sh = smem;
    float* sW = smem + 1024;
    for (int q = tid; q < 1024; q += 256) sh[q] = a.hTX[q];
    sW[tid] = a.Wm[tid & 255];
    __syncthreads();
    for (int i = gtid; i < kN; i += gsz) {
      const float* u = Ucur + (size_t)i * 64;
      float pre[16];
#pragma unroll
      for (int c = 0; c < 16; c++) {
        float s = 0.f;
#pragma unroll
        for (int k = 0; k < 64; k++) s += u[k] * sh[c * 64 + k];
        pre[c] = 0.9f * s + 0.1f * a.hC[(size_t)i * 16 + c];
      }
#pragma unroll
      for (int jj = 0; jj < 16; jj++) {
        float o = 0.f;
#pragma unroll
        for (int c = 0; c < 16; c++) o += pre[c] * sW[c * 16 + jj];
        a.out[(size_t)i * 16 + jj] = o;
      }
    }
  } break;
  }
}

extern "C" void kernel_launch(void* const* d_in, const int* in_sizes, int n_in,
                              void* d_out, int out_size, void* d_ws, size_t ws_size,
                              hipStream_t stream)
{
  const float* x       = (const float*)d_in[0];
  const int*   eidx    = (const int*)d_in[1];
  const float* ew      = (const float*)d_in[2];
  const float* aw      = (const float*)d_in[3];
  const float* connect = (const float*)d_in[4];
  const float* ci      = (const float*)d_in[5];
  const float* lin1_w  = (const float*)d_in[6];
  const float* lin1_b  = (const float*)d_in[7];
  const float* lin2_w  = (const float*)d_in[8];
  const float* lin2_b  = (const float*)d_in[9];
  const float* lin_a_w = (const float*)d_in[10];
  const float* lin_a_b = (const float*)d_in[11];
  const float* lin_n_w = (const float*)d_in[12];
  const float* lin_n_b = (const float*)d_in[13];
  const float* left_w  = (const float*)d_in[14];
  const float* att_w   = (const float*)d_in[15];
  const float* v_w     = (const float*)d_in[16];
  const float* v_b     = (const float*)d_in[17];
  const float* Wm      = (const float*)d_in[18];
  const float* conf_p  = (const float*)d_in[19];
  const float* b_param = (const float*)d_in[20];
  const int* row = eidx;
  const int* col = eidx + kE;
  float* out = (float*)d_out;

  char* base = (char*)d_ws;
  size_t off = 0;
  auto alloc = [&](size_t bytes) -> void* {
    void* p = base + off;
    off += bytes;
    off = (off + 255) & ~(size_t)255;
    return p;
  };
  float* raw   = (float*)alloc((size_t)kN * kNH * 4);
  float* h16   = (float*)alloc((size_t)kN * kC * 4);
  float* hC    = (float*)alloc((size_t)kN * kC * 4);
  float* nei   = (float*)alloc((size_t)kN * kC * 4);
  float* lx    = (float*)alloc((size_t)kN * kC * 4);
  int*   yhat  = (int*)alloc((size_t)kN * 4);
  float* conf  = (float*)alloc((size_t)kE * 4);
  float* Va    = (float*)alloc((size_t)kN * kK * 4);
  float* Vb    = (float*)alloc((size_t)kN * kK * 4);
  float* Ua    = (float*)alloc((size_t)kN * kK * 4);
  float* Ub    = (float*)alloc((size_t)kN * kK * 4);
  float* T     = (float*)alloc((size_t)kN * kK * 4);
  float* score = (float*)alloc((size_t)kE * 4);
  float* G     = (float*)alloc(64 * 64 * 4);
  float* Gi    = (float*)alloc(64 * 64 * 4);
  float* Gp    = (float*)alloc(64 * 64 * 4);
  float* hTX   = (float*)alloc(kC * kK * 4);
  float* Hp    = (float*)alloc(kC * kK * 4);
  int* hist1   = (int*)alloc(65536 * 4);
  int* h2a     = (int*)alloc(65536 * 4);
  int* h2b     = (int*)alloc(65536 * 4);
  SelState* sel = (SelState*)alloc(sizeof(SelState));
  int* cntR    = (int*)alloc((size_t)kN * 4);
  int* cntC    = (int*)alloc((size_t)kN * 4);
  int* fillR   = (int*)alloc((size_t)kN * 4);
  int* fillC   = (int*)alloc((size_t)kN * 4);
  int* startR  = (int*)alloc((size_t)(kN + 1) * 4);
  int* startC  = (int*)alloc((size_t)(kN + 1) * 4);
  int* eR      = (int*)alloc((size_t)kE * 4);
  int* eC      = (int*)alloc((size_t)kE * 4);
  int* othR    = (int*)alloc((size_t)kE * 4);
  int* othC    = (int*)alloc((size_t)kE * 4);
  float* P     = (float*)alloc((size_t)GRAM_PARTS * 5120 * 4);
  const int KpC = 10016, KpX = 512, KpV = 256;
  ushort* BcH = (ushort*)alloc((size_t)256 * KpC * 2);
  ushort* BcL = (ushort*)alloc((size_t)256 * KpC * 2);
  ushort* BxH = (ushort*)alloc((size_t)256 * KpX * 2);
  ushort* BxL = (ushort*)alloc((size_t)256 * KpX * 2);
  ushort* BvH = (ushort*)alloc((size_t)64 * KpV * 2);
  ushort* BvL = (ushort*)alloc((size_t)64 * KpV * 2);
  float* Pbig  = (float*)alloc((size_t)6 * kN * kNH * 4);

  // ---- pre-split weights ----
  split_bf<<<(256 * KpC + 255) / 256, 256, 0, stream>>>(lin_a_w, BcH, BcL, 256, 10000, KpC);
  split_bf<<<(256 * KpX + 255) / 256, 256, 0, stream>>>(lin1_w, BxH, BxL, 256, 500, KpX);
  split_bf<<<(64 * KpV + 255) / 256, 256, 0, stream>>>(v_w, BvH, BvL, 64, 256, KpV);

  // ---- dense front-end (MFMA) ----
  gemm_v3<256, false><<<dim3(157, 1, 6), 256, 0, stream>>>(
      connect, BcH, BcL, nullptr, Pbig, kN, 10000, KpC, 1696, kNH);
  gemm_v3<256, true><<<dim3(157, 1, 1), 256, 0, stream>>>(
      x, BxH, BxL, nullptr, raw, kN, 500, KpX, 512, kNH);
  reduce_raw<<<(kN * kNH / 4 + 255) / 256, 256, 0, stream>>>(
      (const float4*)Pbig, (const float4*)raw, lin_a_b, lin1_b, (float4*)raw,
      cntR, cntC, fillR, fillC, nei);
  gemm_v3<64, true><<<dim3(157, 1, 1), 256, 0, stream>>>(
      raw, BvH, BvL, v_b, Va, kN, 256, KpV, 256, kK);

  // ---- phase args ----
  MegaArgs ma;
  ma.raw = raw; ma.lin2_w = lin2_w; ma.lin2_b = lin2_b;
  ma.row = row; ma.col = col; ma.aw = aw; ma.ew = ew;
  ma.lnw = lin_n_w; ma.lnb = lin_n_b; ma.left_w = left_w; ma.att_w = att_w;
  ma.ci = ci; ma.conf_p = conf_p; ma.b_param = b_param; ma.Wm = Wm;
  ma.h16 = h16; ma.yhat = yhat; ma.nei = nei; ma.hC = hC; ma.lx = lx; ma.conf = conf;
  ma.cntR = cntR; ma.cntC = cntC; ma.fillR = fillR; ma.fillC = fillC;
  ma.startR = startR; ma.startC = startC;
  ma.eR = eR; ma.eC = eC; ma.othR = othR; ma.othC = othC;
  ma.Va = Va; ma.Vb = Vb; ma.Ua = Ua; ma.Ub = Ub; ma.T = T;
  ma.score = score; ma.G = G; ma.Gi = Gi; ma.Gp = Gp; ma.hTX = hTX; ma.Hp = Hp;
  ma.hist1 = hist1; ma.h2a = h2a; ma.h2b = h2b;
  ma.P = P; ma.sel = sel; ma.out = out;

  // ---- phase pipeline: kernel boundary = grid sync ----
  const dim3 pg(PHASE_BLOCKS);
  for (int p = 0; p <= 5; p++) mega_phase<<<pg, 256, 0, stream>>>(ma, p, 0);
  for (int j = 0; j < 4; j++)
    for (int p = 6; p <= 11; p++) mega_phase<<<pg, 256, 0, stream>>>(ma, p, j);
  mega_phase<<<pg, 256, 0, stream>>>(ma, 12, 4);
  mega_phase<<<pg, 256, 0, stream>>>(ma, 13, 4);
  mega_phase<<<pg, 256, 0, stream>>>(ma, 14, 4);
}